// Round 3
// baseline (314.337 us; speedup 1.0000x reference)
//
#include <hip/hip_runtime.h>

// VectorQuantizer on MI355X — round 3: single-pass fp16 MFMA + exact rescue.
// z: [32,256,32,32] fp32; codebook: [1024,256] fp32; N=32768, K=1024, C=256.
// dist = |e|^2 - 2 z.e (|z|^2 argmin-invariant). Approx z.e: one fp16 MFMA pass
// (err sigma ~0.02 per dist); tokens with approx top-2 gap <= DELTA=0.3 (~8 sigma)
// get exact fp32 rescan. LDS tiles XOR-swizzled (chunk c of row r at c^(r&7),
// folded into the GLOBAL source address so global_load_lds stays lane-linear).
//
// d_out doubles as scratch: zh f16 plane @ bytes [0, 16777216) (epilogue rewrites).
// ws layout (bytes):
//   eh      @ 0        _Float16[1024*256]   (524288)
//   enorm   @ 524288   float[1024]
//   p1      @ 528384   u64[32768]  packed (key|idx) global min
//   p2      @ 790528   u64[32768]  packed global second-min
//   idx     @ 1052672  int[32768]
//   counts  @ 1183744  int[1024]
//   lsum    @ 1187840  float
//   nflag   @ 1187904  int
//   flag    @ 1187968  int[32768]

#define BETA  0.25f
#define DELTA 0.3f

typedef _Float16 half8 __attribute__((ext_vector_type(8)));
typedef float    f32x4 __attribute__((ext_vector_type(4)));
typedef unsigned long long u64;

#define GLOAD_LDS16(g, l) \
    __builtin_amdgcn_global_load_lds((const __attribute__((address_space(1))) unsigned int*)(g), \
                                     (__attribute__((address_space(3))) unsigned int*)(l), 16, 0, 0)

__device__ inline u64 packdi(float v, int idx) {
    unsigned int u = __float_as_uint(v);
    unsigned int key = (u & 0x80000000u) ? ~u : (u | 0x80000000u);
    return ((u64)key << 32) | (unsigned int)idx;
}
__device__ inline float unkeyf(unsigned int k) {
    unsigned int u = (k & 0x80000000u) ? (k ^ 0x80000000u) : ~k;
    return __uint_as_float(u);
}

// ---------------------------------------------------------------------------
// Kernel 1: codebook -> eh f16 + exact |e|^2 + init accumulators. grid 256.
// ---------------------------------------------------------------------------
__global__ __launch_bounds__(256) void vq_prep_cb(
    const float* __restrict__ cb, _Float16* __restrict__ eh,
    float* __restrict__ enorm, u64* __restrict__ p1, u64* __restrict__ p2,
    int* __restrict__ counts, float* __restrict__ lsum, int* __restrict__ nflag)
{
    const int tid = threadIdx.x;
    const int gi  = blockIdx.x * 256 + tid;
    if (gi < 32768) p1[gi] = ~0ull; else p2[gi - 32768] = ~0ull;
    if (blockIdx.x < 4) counts[blockIdx.x * 256 + tid] = 0;
    if (gi == 0) { *lsum = 0.0f; *nflag = 0; }

    const int lane = tid & 63;
    const int r    = blockIdx.x * 4 + (tid >> 6);
    const float4 v = *reinterpret_cast<const float4*>(cb + r * 256 + lane * 4);
    _Float16 h0 = (_Float16)v.x, h1 = (_Float16)v.y, h2 = (_Float16)v.z, h3 = (_Float16)v.w;
    *reinterpret_cast<ushort4*>(eh + r * 256 + lane * 4) =
        make_ushort4(*(unsigned short*)&h0, *(unsigned short*)&h1,
                     *(unsigned short*)&h2, *(unsigned short*)&h3);
    float s = v.x * v.x + v.y * v.y + v.z * v.z + v.w * v.w;
    #pragma unroll
    for (int off = 32; off > 0; off >>= 1) s += __shfl_down(s, off);
    if (lane == 0) enorm[r] = s;
}

// ---------------------------------------------------------------------------
// Kernel 2: z [b][c][hw] -> zh f16 token-major [n][256]. No LDS: thread owns
// (token t, channel-quarter q); reads are lane-coalesced along hw, the 8
// half8 stores fill exactly one 128B line per (t,q). grid 512.
// ---------------------------------------------------------------------------
__global__ __launch_bounds__(256) void vq_prep_z(
    const float* __restrict__ z, _Float16* __restrict__ zh)
{
    const int tid = threadIdx.x;
    const int n0  = blockIdx.x * 64;
    const int t   = tid & 63;
    const int q   = tid >> 6;        // wave-uniform
    const float* zb = z + (n0 >> 10) * 262144 + (n0 & 1023) + t;
    _Float16*    ob = zh + (size_t)(n0 + t) * 256;
    #pragma unroll
    for (int c0 = q * 64; c0 < q * 64 + 64; c0 += 8) {
        half8 h;
        #pragma unroll
        for (int j = 0; j < 8; ++j) h[j] = (_Float16)zb[(c0 + j) * 1024];
        *reinterpret_cast<half8*>(ob + c0) = h;
    }
}

// ---------------------------------------------------------------------------
// Kernel 3: single-pass f16 MFMA distance GEMM + per-block top-2, merged via
// packed atomicMin. grid (256,8); 128x128/block, 4 waves of 64x64, K-chunk 64.
// LDS rows = 128B (64 halves); chunk c of row r stored at c^(r&7) (swizzle in
// global src addr). Frag reads land <=2-way on banks (free).
// ---------------------------------------------------------------------------
__global__ __launch_bounds__(256) void vq_mfma(
    const _Float16* __restrict__ zh, const _Float16* __restrict__ eh,
    const float* __restrict__ enorm, u64* __restrict__ p1, u64* __restrict__ p2)
{
    __shared__ _Float16 sA[128 * 64], sB[128 * 64];
    __shared__ float lm1[2][128], lm2[2][128];
    __shared__ int   li1[2][128];

    const int tid  = threadIdx.x;
    const int lane = tid & 63;
    const int wv   = tid >> 6;
    const int wm   = wv >> 1, wn = wv & 1;
    const int n0   = blockIdx.x * 128;
    const int k0   = blockIdx.y * 128;

    // staging: call p stages rows [p*32, p*32+32); lane's LDS dest is linear
    // (tid*16B), so lane fetches logical chunk lc = (tid&7)^(row&7) from global.
    const int srow = tid >> 3;                    // 0..31
    const int lc   = (tid & 7) ^ (srow & 7);
    const _Float16* gA = zh + (size_t)(n0 + srow) * 256 + lc * 8;
    const _Float16* gB = eh + (size_t)(k0 + srow) * 256 + lc * 8;
    _Float16* lA = &sA[tid * 8];
    _Float16* lB = &sB[tid * 8];

    const int arow = wm * 64 + (lane & 15);       // arow&7 == lane&7
    const int brow = wn * 64 + (lane & 15);
    const int g    = lane >> 4;
    const int x7   = lane & 7;

    f32x4 acc[4][4] = {};

    for (int kc = 0; kc < 4; ++kc) {
        const int off = kc * 64;
        #pragma unroll
        for (int p = 0; p < 4; ++p) {
            GLOAD_LDS16(gA + p * 8192 + off, lA + p * 2048);
            GLOAD_LDS16(gB + p * 8192 + off, lB + p * 2048);
        }
        __syncthreads();
        #pragma unroll
        for (int kk = 0; kk < 2; ++kk) {
            const int pc = (((kk * 4) + g) ^ x7) * 8;   // swizzled chunk offset
            half8 a[4], b[4];
            #pragma unroll
            for (int mt = 0; mt < 4; ++mt)
                a[mt] = *reinterpret_cast<const half8*>(&sA[(arow + mt * 16) * 64 + pc]);
            #pragma unroll
            for (int nt = 0; nt < 4; ++nt)
                b[nt] = *reinterpret_cast<const half8*>(&sB[(brow + nt * 16) * 64 + pc]);
            #pragma unroll
            for (int mt = 0; mt < 4; ++mt)
                #pragma unroll
                for (int nt = 0; nt < 4; ++nt)
                    acc[mt][nt] = __builtin_amdgcn_mfma_f32_16x16x32_f16(a[mt], b[nt], acc[mt][nt], 0, 0, 0);
        }
        __syncthreads();
    }

    // top-2 epilogue. D layout: row=(lane>>4)*4+reg, col=lane&15 [m89-verified]
    const int cbase = k0 + wn * 64 + (lane & 15);
    float en_v[4];
    #pragma unroll
    for (int nt = 0; nt < 4; ++nt) en_v[nt] = enorm[cbase + nt * 16];

    #pragma unroll
    for (int mt = 0; mt < 4; ++mt) {
        #pragma unroll
        for (int reg = 0; reg < 4; ++reg) {
            const int tloc = wm * 64 + mt * 16 + (lane >> 4) * 4 + reg;
            float m1 = 1e30f, m2 = 1e30f; int i1 = 0x7fffffff;
            #pragma unroll
            for (int nt = 0; nt < 4; ++nt) {
                const float d = fmaf(-2.0f, acc[mt][nt][reg], en_v[nt]);
                if (d < m1) { m2 = m1; m1 = d; i1 = cbase + nt * 16; }
                else        { m2 = fminf(m2, d); }
            }
            #pragma unroll
            for (int off = 1; off < 16; off <<= 1) {
                const float om1 = __shfl_xor(m1, off);
                const int   oi1 = __shfl_xor(i1, off);
                const float om2 = __shfl_xor(m2, off);
                if (om1 < m1 || (om1 == m1 && oi1 < i1)) { m2 = fminf(m1, om2); m1 = om1; i1 = oi1; }
                else                                     { m2 = fminf(m2, om1); }
            }
            if ((lane & 15) == 0) { lm1[wn][tloc] = m1; li1[wn][tloc] = i1; lm2[wn][tloc] = m2; }
        }
    }
    __syncthreads();
    if (tid < 128) {
        const float a1 = lm1[0][tid], a2 = lm2[0][tid];
        const int   ai = li1[0][tid];
        const float b1 = lm1[1][tid], b2 = lm2[1][tid];
        const int   bi = li1[1][tid];
        float m1, m2; int i1;
        if (b1 < a1 || (b1 == a1 && bi < ai)) { m1 = b1; i1 = bi; m2 = fminf(a1, b2); }
        else                                  { m1 = a1; i1 = ai; m2 = fminf(a2, b1); }
        const int n = n0 + tid;
        const u64 me1 = packdi(m1, i1);
        const u64 me2 = packdi(m2, 0x7fffffff);
        const u64 old = atomicMin(&p1[n], me1);
        const u64 loser = old > me1 ? old : me1;
        atomicMin(&p2[n], loser < me2 ? loser : me2);
    }
}

// ---------------------------------------------------------------------------
// Kernel 4: unpack top-2 -> idx; flag tokens with approx gap <= DELTA.
// ---------------------------------------------------------------------------
__global__ __launch_bounds__(256) void vq_reduce_flag(
    const u64* __restrict__ p1, const u64* __restrict__ p2,
    int* __restrict__ idx, int* __restrict__ nflag, int* __restrict__ flaglist)
{
    const int n = blockIdx.x * 256 + threadIdx.x;
    const u64 a = p1[n], b = p2[n];
    const int i1 = (int)(a & 0xffffffffu);
    idx[n] = i1;
    const float v1 = unkeyf((unsigned int)(a >> 32));
    const float v2 = unkeyf((unsigned int)(b >> 32));
    if (v2 - v1 <= DELTA) {
        const int p = atomicAdd(nflag, 1);
        flaglist[p] = n;
    }
}

// ---------------------------------------------------------------------------
// Kernel 5: exact fp32 rescan for flagged tokens. grid 256 fixed (graph-safe).
// ---------------------------------------------------------------------------
__global__ __launch_bounds__(256) void vq_rescue(
    const float* __restrict__ z, const float* __restrict__ cb,
    const float* __restrict__ enorm, const int* __restrict__ nflag,
    const int* __restrict__ flaglist, int* __restrict__ idx)
{
    __shared__ float zs[256];
    __shared__ float rv[256];
    __shared__ int   ri[256];
    const int tid = threadIdx.x;
    const int count = *nflag;
    for (int i = blockIdx.x; i < count; i += 256) {
        const int n = flaglist[i];
        zs[tid] = z[(n >> 10) * 262144 + tid * 1024 + (n & 1023)];
        __syncthreads();
        float bv = 1e30f; int bi = 0x7fffffff;
        #pragma unroll
        for (int j = 0; j < 4; ++j) {
            const int k = tid * 4 + j;
            const float* er = cb + k * 256;
            float s = 0.0f;
            for (int c = 0; c < 256; c += 4) {
                const float4 e4 = *reinterpret_cast<const float4*>(er + c);
                s = fmaf(e4.x, zs[c], s);
                s = fmaf(e4.y, zs[c + 1], s);
                s = fmaf(e4.z, zs[c + 2], s);
                s = fmaf(e4.w, zs[c + 3], s);
            }
            const float d = fmaf(-2.0f, s, enorm[k]);
            if (d < bv) { bv = d; bi = k; }
        }
        rv[tid] = bv; ri[tid] = bi;
        __syncthreads();
        for (int s = 128; s > 0; s >>= 1) {
            if (tid < s) {
                const float ov = rv[tid + s]; const int oi = ri[tid + s];
                if (ov < rv[tid] || (ov == rv[tid] && oi < ri[tid])) { rv[tid] = ov; ri[tid] = oi; }
            }
            __syncthreads();
        }
        if (tid == 0) idx[n] = ri[0];
        __syncthreads();
    }
}

// ---------------------------------------------------------------------------
// Kernel 6: gather z_q -> out, fused sum((z_q-z)^2) + histogram. grid 512.
// ---------------------------------------------------------------------------
__global__ __launch_bounds__(256) void vq_epilogue(
    const float* __restrict__ z, const float* __restrict__ cb,
    const int* __restrict__ idx, float* __restrict__ out,
    int* __restrict__ counts, float* __restrict__ lsum)
{
    __shared__ int   sidx[64];
    __shared__ float swsum[4];
    const int tid = threadIdx.x;
    const int n0  = blockIdx.x * 64;
    if (tid < 64) {
        const int ii = idx[n0 + tid];
        sidx[tid] = ii;
        atomicAdd(&counts[ii], 1);
    }
    __syncthreads();
    const float* zb = z   + (n0 >> 10) * 262144 + (n0 & 1023);
    float*       ob = out + (n0 >> 10) * 262144 + (n0 & 1023);
    const int t  = tid & 63;
    const int cg = tid >> 6;
    const int row = sidx[t] << 8;
    float sum = 0.0f;
    for (int c = cg; c < 256; c += 4) {
        const float q  = cb[row + c];
        const float zv = zb[c * 1024 + t];
        const float d  = q - zv;
        sum = fmaf(d, d, sum);
        ob[c * 1024 + t] = q;
    }
    #pragma unroll
    for (int off = 32; off > 0; off >>= 1) sum += __shfl_down(sum, off);
    if ((tid & 63) == 0) swsum[tid >> 6] = sum;
    __syncthreads();
    if (tid == 0) atomicAdd(lsum, swsum[0] + swsum[1] + swsum[2] + swsum[3]);
}

// ---------------------------------------------------------------------------
// Kernel 7: scalars.
// ---------------------------------------------------------------------------
__global__ __launch_bounds__(256) void vq_finalize(
    const int* __restrict__ counts, const float* __restrict__ lsum,
    float* __restrict__ outs)
{
    __shared__ float ssum[4];
    const int tid = threadIdx.x;
    float local = 0.0f;
    #pragma unroll
    for (int k = tid; k < 1024; k += 256) {
        float p = (float)counts[k] * (1.0f / 32768.0f);
        p = fmaxf(p, 1e-10f);
        local += p * logf(p);
    }
    #pragma unroll
    for (int off = 32; off > 0; off >>= 1) local += __shfl_down(local, off);
    if ((tid & 63) == 0) ssum[tid >> 6] = local;
    __syncthreads();
    if (tid == 0) {
        const float ent = ssum[0] + ssum[1] + ssum[2] + ssum[3];
        outs[0] = lsum[0] * ((1.0f + BETA) / 8388608.0f);
        outs[1] = expf(-ent);
    }
}

extern "C" void kernel_launch(void* const* d_in, const int* in_sizes, int n_in,
                              void* d_out, int out_size, void* d_ws, size_t ws_size,
                              hipStream_t stream)
{
    const float* z  = (const float*)d_in[0];
    const float* cb = (const float*)d_in[1];
    float* out = (float*)d_out;

    _Float16* zh = (_Float16*)d_out;   // scratch; epilogue rewrites all of out

    char* ws = (char*)d_ws;
    _Float16* eh     = (_Float16*)(ws);
    float*    enorm  = (float*)   (ws + 524288);
    u64*      p1     = (u64*)     (ws + 528384);
    u64*      p2     = (u64*)     (ws + 790528);
    int*      idx    = (int*)     (ws + 1052672);
    int*      counts = (int*)     (ws + 1183744);
    float*    lsum   = (float*)   (ws + 1187840);
    int*      nflag  = (int*)     (ws + 1187904);
    int*      flag   = (int*)     (ws + 1187968);

    vq_prep_cb    <<<256, 256, 0, stream>>>(cb, eh, enorm, p1, p2, counts, lsum, nflag);
    vq_prep_z     <<<512, 256, 0, stream>>>(z, zh);
    vq_mfma       <<<dim3(256, 8), 256, 0, stream>>>(zh, eh, enorm, p1, p2);
    vq_reduce_flag<<<128, 256, 0, stream>>>(p1, p2, idx, nflag, flag);
    vq_rescue     <<<256, 256, 0, stream>>>(z, cb, enorm, nflag, flag, idx);
    vq_epilogue   <<<512, 256, 0, stream>>>(z, cb, idx, out, counts, lsum);
    vq_finalize   <<<1, 256, 0, stream>>>(counts, lsum, out + 8388608);
}

// Round 4
// 225.417 us; speedup vs baseline: 1.3945x; 1.3945x over previous
//
#include <hip/hip_runtime.h>

// VectorQuantizer on MI355X — round 4: single-pass fp16 MFMA + batched rescue.
// z: [32,256,32,32] fp32; codebook: [1024,256] fp32; N=32768, K=1024, C=256.
// dist = |e|^2 - 2 z.e (|z|^2 argmin-invariant). Approx z.e: one fp16 MFMA pass
// (err sigma ~0.02 per dist); tokens with approx top-2 gap <= DELTA=0.3 get an
// exact fp32 full rescan (4 tokens/block, codebook reuse x4).
//
// d_out doubles as scratch: zh f16 plane @ bytes [0, 16777216) (epilogue rewrites).
// ws layout (bytes):
//   eh      @ 0        _Float16[1024*256]   (524288)
//   enorm   @ 524288   float[1024]
//   p1      @ 528384   u64[32768]  packed (key|idx) global min
//   p2      @ 790528   u64[32768]  packed global second-min
//   idx     @ 1052672  int[32768]
//   counts  @ 1183744  int[1024]
//   lsum    @ 1187840  float
//   nflag   @ 1187904  int
//   flag    @ 1187968  int[32768]

#define BETA  0.25f
#define DELTA 0.3f

typedef _Float16 half8 __attribute__((ext_vector_type(8)));
typedef float    f32x4 __attribute__((ext_vector_type(4)));
typedef unsigned long long u64;

#define GLOAD_LDS16(g, l) \
    __builtin_amdgcn_global_load_lds((const __attribute__((address_space(1))) unsigned int*)(g), \
                                     (__attribute__((address_space(3))) unsigned int*)(l), 16, 0, 0)

__device__ inline u64 packdi(float v, int idx) {
    unsigned int u = __float_as_uint(v);
    unsigned int key = (u & 0x80000000u) ? ~u : (u | 0x80000000u);
    return ((u64)key << 32) | (unsigned int)idx;
}
__device__ inline float unkeyf(unsigned int k) {
    unsigned int u = (k & 0x80000000u) ? (k ^ 0x80000000u) : ~k;
    return __uint_as_float(u);
}

// ---------------------------------------------------------------------------
// Kernel 1: codebook -> eh f16 + exact |e|^2 + init accumulators. grid 256.
// ---------------------------------------------------------------------------
__global__ __launch_bounds__(256) void vq_prep_cb(
    const float* __restrict__ cb, _Float16* __restrict__ eh,
    float* __restrict__ enorm, u64* __restrict__ p1, u64* __restrict__ p2,
    int* __restrict__ counts, float* __restrict__ lsum, int* __restrict__ nflag)
{
    const int tid = threadIdx.x;
    const int gi  = blockIdx.x * 256 + tid;
    if (gi < 32768) p1[gi] = ~0ull; else p2[gi - 32768] = ~0ull;
    if (blockIdx.x < 4) counts[blockIdx.x * 256 + tid] = 0;
    if (gi == 0) { *lsum = 0.0f; *nflag = 0; }

    const int lane = tid & 63;
    const int r    = blockIdx.x * 4 + (tid >> 6);
    const float4 v = *reinterpret_cast<const float4*>(cb + r * 256 + lane * 4);
    _Float16 h0 = (_Float16)v.x, h1 = (_Float16)v.y, h2 = (_Float16)v.z, h3 = (_Float16)v.w;
    *reinterpret_cast<ushort4*>(eh + r * 256 + lane * 4) =
        make_ushort4(*(unsigned short*)&h0, *(unsigned short*)&h1,
                     *(unsigned short*)&h2, *(unsigned short*)&h3);
    float s = v.x * v.x + v.y * v.y + v.z * v.z + v.w * v.w;
    #pragma unroll
    for (int off = 32; off > 0; off >>= 1) s += __shfl_down(s, off);
    if (lane == 0) enorm[r] = s;
}

// ---------------------------------------------------------------------------
// Kernel 2: z [b][c][hw] -> zh f16 token-major [n][256]. grid 512.
// ---------------------------------------------------------------------------
__global__ __launch_bounds__(256) void vq_prep_z(
    const float* __restrict__ z, _Float16* __restrict__ zh)
{
    const int tid = threadIdx.x;
    const int n0  = blockIdx.x * 64;
    const int t   = tid & 63;
    const int q   = tid >> 6;        // wave-uniform
    const float* zb = z + (n0 >> 10) * 262144 + (n0 & 1023) + t;
    _Float16*    ob = zh + (size_t)(n0 + t) * 256;
    #pragma unroll
    for (int c0 = q * 64; c0 < q * 64 + 64; c0 += 8) {
        half8 h;
        #pragma unroll
        for (int j = 0; j < 8; ++j) h[j] = (_Float16)zb[(c0 + j) * 1024];
        *reinterpret_cast<half8*>(ob + c0) = h;
    }
}

// ---------------------------------------------------------------------------
// Kernel 3: single-pass f16 MFMA distance GEMM + per-block top-2, merged via
// packed atomicMin. grid (256,8); 128x128/block, 4 waves of 64x64, K-chunk 64.
// LDS rows = 128B; chunk c of row r stored at c^(r&7) (swizzle folded into
// the global source address; global_load_lds dest stays lane-linear).
// ---------------------------------------------------------------------------
__global__ __launch_bounds__(256) void vq_mfma(
    const _Float16* __restrict__ zh, const _Float16* __restrict__ eh,
    const float* __restrict__ enorm, u64* __restrict__ p1, u64* __restrict__ p2)
{
    __shared__ _Float16 sA[128 * 64], sB[128 * 64];
    __shared__ float lm1[2][128], lm2[2][128];
    __shared__ int   li1[2][128];

    const int tid  = threadIdx.x;
    const int lane = tid & 63;
    const int wv   = tid >> 6;
    const int wm   = wv >> 1, wn = wv & 1;
    const int n0   = blockIdx.x * 128;
    const int k0   = blockIdx.y * 128;

    const int srow = tid >> 3;                    // 0..31
    const int lc   = (tid & 7) ^ (srow & 7);
    const _Float16* gA = zh + (size_t)(n0 + srow) * 256 + lc * 8;
    const _Float16* gB = eh + (size_t)(k0 + srow) * 256 + lc * 8;
    _Float16* lA = &sA[tid * 8];
    _Float16* lB = &sB[tid * 8];

    const int arow = wm * 64 + (lane & 15);
    const int brow = wn * 64 + (lane & 15);
    const int g    = lane >> 4;
    const int x7   = lane & 7;

    f32x4 acc[4][4] = {};

    for (int kc = 0; kc < 4; ++kc) {
        const int off = kc * 64;
        #pragma unroll
        for (int p = 0; p < 4; ++p) {
            GLOAD_LDS16(gA + p * 8192 + off, lA + p * 2048);
            GLOAD_LDS16(gB + p * 8192 + off, lB + p * 2048);
        }
        __syncthreads();
        #pragma unroll
        for (int kk = 0; kk < 2; ++kk) {
            const int pc = (((kk * 4) + g) ^ x7) * 8;
            half8 a[4], b[4];
            #pragma unroll
            for (int mt = 0; mt < 4; ++mt)
                a[mt] = *reinterpret_cast<const half8*>(&sA[(arow + mt * 16) * 64 + pc]);
            #pragma unroll
            for (int nt = 0; nt < 4; ++nt)
                b[nt] = *reinterpret_cast<const half8*>(&sB[(brow + nt * 16) * 64 + pc]);
            #pragma unroll
            for (int mt = 0; mt < 4; ++mt)
                #pragma unroll
                for (int nt = 0; nt < 4; ++nt)
                    acc[mt][nt] = __builtin_amdgcn_mfma_f32_16x16x32_f16(a[mt], b[nt], acc[mt][nt], 0, 0, 0);
        }
        __syncthreads();
    }

    // top-2 epilogue. D layout: row=(lane>>4)*4+reg, col=lane&15 [m89-verified]
    const int cbase = k0 + wn * 64 + (lane & 15);
    float en_v[4];
    #pragma unroll
    for (int nt = 0; nt < 4; ++nt) en_v[nt] = enorm[cbase + nt * 16];

    #pragma unroll
    for (int mt = 0; mt < 4; ++mt) {
        #pragma unroll
        for (int reg = 0; reg < 4; ++reg) {
            const int tloc = wm * 64 + mt * 16 + (lane >> 4) * 4 + reg;
            float m1 = 1e30f, m2 = 1e30f; int i1 = 0x7fffffff;
            #pragma unroll
            for (int nt = 0; nt < 4; ++nt) {
                const float d = fmaf(-2.0f, acc[mt][nt][reg], en_v[nt]);
                if (d < m1) { m2 = m1; m1 = d; i1 = cbase + nt * 16; }
                else        { m2 = fminf(m2, d); }
            }
            #pragma unroll
            for (int off = 1; off < 16; off <<= 1) {
                const float om1 = __shfl_xor(m1, off);
                const int   oi1 = __shfl_xor(i1, off);
                const float om2 = __shfl_xor(m2, off);
                if (om1 < m1 || (om1 == m1 && oi1 < i1)) { m2 = fminf(m1, om2); m1 = om1; i1 = oi1; }
                else                                     { m2 = fminf(m2, om1); }
            }
            if ((lane & 15) == 0) { lm1[wn][tloc] = m1; li1[wn][tloc] = i1; lm2[wn][tloc] = m2; }
        }
    }
    __syncthreads();
    if (tid < 128) {
        const float a1 = lm1[0][tid], a2 = lm2[0][tid];
        const int   ai = li1[0][tid];
        const float b1 = lm1[1][tid], b2 = lm2[1][tid];
        const int   bi = li1[1][tid];
        float m1, m2; int i1;
        if (b1 < a1 || (b1 == a1 && bi < ai)) { m1 = b1; i1 = bi; m2 = fminf(a1, b2); }
        else                                  { m1 = a1; i1 = ai; m2 = fminf(a2, b1); }
        const int n = n0 + tid;
        const u64 me1 = packdi(m1, i1);
        const u64 me2 = packdi(m2, 0x7fffffff);
        const u64 old = atomicMin(&p1[n], me1);
        const u64 loser = old > me1 ? old : me1;
        atomicMin(&p2[n], loser < me2 ? loser : me2);
    }
}

// ---------------------------------------------------------------------------
// Kernel 4: unpack top-2 -> idx; flag tokens with approx gap <= DELTA.
// ---------------------------------------------------------------------------
__global__ __launch_bounds__(256) void vq_reduce_flag(
    const u64* __restrict__ p1, const u64* __restrict__ p2,
    int* __restrict__ idx, int* __restrict__ nflag, int* __restrict__ flaglist)
{
    const int n = blockIdx.x * 256 + threadIdx.x;
    const u64 a = p1[n], b = p2[n];
    const int i1 = (int)(a & 0xffffffffu);
    idx[n] = i1;
    const float v1 = unkeyf((unsigned int)(a >> 32));
    const float v2 = unkeyf((unsigned int)(b >> 32));
    if (v2 - v1 <= DELTA) {
        const int p = atomicAdd(nflag, 1);
        flaglist[p] = n;
    }
}

// ---------------------------------------------------------------------------
// Kernel 5: exact fp32 rescan, 4 tokens/block (codebook L2 reuse x4).
// grid 256 x 512 threads. Thread scans 2 codes against 4 staged z-vectors;
// per-token argmin via LDS fold + one wave per token. First-occurrence ties.
// ---------------------------------------------------------------------------
__global__ __launch_bounds__(512) void vq_rescue(
    const float* __restrict__ z, const float* __restrict__ cb,
    const float* __restrict__ enorm, const int* __restrict__ nflag,
    const int* __restrict__ flaglist, int* __restrict__ idx)
{
    __shared__ float zs[4][256];
    __shared__ float rv[4][512];
    __shared__ int   ri[4][512];
    const int tid = threadIdx.x;
    const int count = *nflag;
    for (int base = blockIdx.x * 4; base < count; base += 1024) {
        const int nt = min(4, count - base);
        __syncthreads();   // previous iteration fully done with zs/rv/ri
        for (int t = tid >> 8; t < nt; t += 2) {
            const int n = flaglist[base + t];
            const int c = tid & 255;
            zs[t][c] = z[(n >> 10) * 262144 + c * 1024 + (n & 1023)];
        }
        __syncthreads();
        float bv[4] = {1e30f, 1e30f, 1e30f, 1e30f};
        int   bi[4] = {0x7fffffff, 0x7fffffff, 0x7fffffff, 0x7fffffff};
        #pragma unroll
        for (int j = 0; j < 2; ++j) {
            const int k = tid * 2 + j;
            const float* er = cb + k * 256;
            float s0 = 0.f, s1 = 0.f, s2 = 0.f, s3 = 0.f;
            #pragma unroll 4
            for (int c = 0; c < 256; c += 4) {
                const float4 e4 = *reinterpret_cast<const float4*>(er + c);
                s0 = fmaf(e4.x, zs[0][c], fmaf(e4.y, zs[0][c+1], fmaf(e4.z, zs[0][c+2], fmaf(e4.w, zs[0][c+3], s0))));
                s1 = fmaf(e4.x, zs[1][c], fmaf(e4.y, zs[1][c+1], fmaf(e4.z, zs[1][c+2], fmaf(e4.w, zs[1][c+3], s1))));
                s2 = fmaf(e4.x, zs[2][c], fmaf(e4.y, zs[2][c+1], fmaf(e4.z, zs[2][c+2], fmaf(e4.w, zs[2][c+3], s2))));
                s3 = fmaf(e4.x, zs[3][c], fmaf(e4.y, zs[3][c+1], fmaf(e4.z, zs[3][c+2], fmaf(e4.w, zs[3][c+3], s3))));
            }
            const float en = enorm[k];
            float d;
            d = fmaf(-2.0f, s0, en); if (d < bv[0]) { bv[0] = d; bi[0] = k; }
            d = fmaf(-2.0f, s1, en); if (d < bv[1]) { bv[1] = d; bi[1] = k; }
            d = fmaf(-2.0f, s2, en); if (d < bv[2]) { bv[2] = d; bi[2] = k; }
            d = fmaf(-2.0f, s3, en); if (d < bv[3]) { bv[3] = d; bi[3] = k; }
        }
        #pragma unroll
        for (int t = 0; t < 4; ++t) { rv[t][tid] = bv[t]; ri[t][tid] = bi[t]; }
        __syncthreads();
        const int wv = tid >> 6, lane = tid & 63;
        if (wv < nt) {
            float m = rv[wv][lane]; int mi = ri[wv][lane];
            #pragma unroll
            for (int s = 1; s < 8; ++s) {
                const float v = rv[wv][lane + s * 64]; const int ii = ri[wv][lane + s * 64];
                if (v < m || (v == m && ii < mi)) { m = v; mi = ii; }
            }
            #pragma unroll
            for (int off = 32; off > 0; off >>= 1) {
                const float ov = __shfl_down(m, off); const int oi = __shfl_down(mi, off);
                if (ov < m || (ov == m && oi < mi)) { m = ov; mi = oi; }
            }
            if (lane == 0) idx[flaglist[base + wv]] = mi;
        }
    }
}

// ---------------------------------------------------------------------------
// Kernel 6: gather z_q -> out, fused sum((z_q-z)^2) + histogram. grid 512.
// ---------------------------------------------------------------------------
__global__ __launch_bounds__(256) void vq_epilogue(
    const float* __restrict__ z, const float* __restrict__ cb,
    const int* __restrict__ idx, float* __restrict__ out,
    int* __restrict__ counts, float* __restrict__ lsum)
{
    __shared__ int   sidx[64];
    __shared__ float swsum[4];
    const int tid = threadIdx.x;
    const int n0  = blockIdx.x * 64;
    if (tid < 64) {
        const int ii = idx[n0 + tid];
        sidx[tid] = ii;
        atomicAdd(&counts[ii], 1);
    }
    __syncthreads();
    const float* zb = z   + (n0 >> 10) * 262144 + (n0 & 1023);
    float*       ob = out + (n0 >> 10) * 262144 + (n0 & 1023);
    const int t  = tid & 63;
    const int cg = tid >> 6;
    const int row = sidx[t] << 8;
    float sum = 0.0f;
    for (int c = cg; c < 256; c += 4) {
        const float q  = cb[row + c];
        const float zv = zb[c * 1024 + t];
        const float d  = q - zv;
        sum = fmaf(d, d, sum);
        ob[c * 1024 + t] = q;
    }
    #pragma unroll
    for (int off = 32; off > 0; off >>= 1) sum += __shfl_down(sum, off);
    if ((tid & 63) == 0) swsum[tid >> 6] = sum;
    __syncthreads();
    if (tid == 0) atomicAdd(lsum, swsum[0] + swsum[1] + swsum[2] + swsum[3]);
}

// ---------------------------------------------------------------------------
// Kernel 7: scalars.
// ---------------------------------------------------------------------------
__global__ __launch_bounds__(256) void vq_finalize(
    const int* __restrict__ counts, const float* __restrict__ lsum,
    float* __restrict__ outs)
{
    __shared__ float ssum[4];
    const int tid = threadIdx.x;
    float local = 0.0f;
    #pragma unroll
    for (int k = tid; k < 1024; k += 256) {
        float p = (float)counts[k] * (1.0f / 32768.0f);
        p = fmaxf(p, 1e-10f);
        local += p * logf(p);
    }
    #pragma unroll
    for (int off = 32; off > 0; off >>= 1) local += __shfl_down(local, off);
    if ((tid & 63) == 0) ssum[tid >> 6] = local;
    __syncthreads();
    if (tid == 0) {
        const float ent = ssum[0] + ssum[1] + ssum[2] + ssum[3];
        outs[0] = lsum[0] * ((1.0f + BETA) / 8388608.0f);
        outs[1] = expf(-ent);
    }
}

extern "C" void kernel_launch(void* const* d_in, const int* in_sizes, int n_in,
                              void* d_out, int out_size, void* d_ws, size_t ws_size,
                              hipStream_t stream)
{
    const float* z  = (const float*)d_in[0];
    const float* cb = (const float*)d_in[1];
    float* out = (float*)d_out;

    _Float16* zh = (_Float16*)d_out;   // scratch; epilogue rewrites all of out

    char* ws = (char*)d_ws;
    _Float16* eh     = (_Float16*)(ws);
    float*    enorm  = (float*)   (ws + 524288);
    u64*      p1     = (u64*)     (ws + 528384);
    u64*      p2     = (u64*)     (ws + 790528);
    int*      idx    = (int*)     (ws + 1052672);
    int*      counts = (int*)     (ws + 1183744);
    float*    lsum   = (float*)   (ws + 1187840);
    int*      nflag  = (int*)     (ws + 1187904);
    int*      flag   = (int*)     (ws + 1187968);

    vq_prep_cb    <<<256, 256, 0, stream>>>(cb, eh, enorm, p1, p2, counts, lsum, nflag);
    vq_prep_z     <<<512, 256, 0, stream>>>(z, zh);
    vq_mfma       <<<dim3(256, 8), 256, 0, stream>>>(zh, eh, enorm, p1, p2);
    vq_reduce_flag<<<128, 256, 0, stream>>>(p1, p2, idx, nflag, flag);
    vq_rescue     <<<256, 512, 0, stream>>>(z, cb, enorm, nflag, flag, idx);
    vq_epilogue   <<<512, 256, 0, stream>>>(z, cb, idx, out, counts, lsum);
    vq_finalize   <<<1, 256, 0, stream>>>(counts, lsum, out + 8388608);
}